// Round 7
// baseline (138.408 us; speedup 1.0000x reference)
//
#include <hip/hip_runtime.h>
#include <hip/hip_bf16.h>

// out[b,n] = sum_k cos(x[b,k] * mean(phases[k,:])) * W[k,n]
// B = 4096, K = 1024, N = 4096, NQ = 12. All fp32 in/out.
//
// Round 7: single-term f16 on the ROUND-3-PROVEN structure (its 46%-util
// 2-barrier loop was the best measured: 1054 TF effective). Changes vs r3:
//   - drop the Al low-term (validated rounds 4-6): MFMA work halves
//   - LDS 49KB -> 32KB => 5 blocks/CU by LDS (4 by grid) => ~16 waves/CU,
//     fixing the occupancy starvation that capped rounds 4-6 at 775 TF
//   - bijective XCD chunk swizzle (1024 wgs % 8 == 0)
// Producers byte-identical to round 3's proven 128-row x 64-k swizzled tiles
// (measured ZERO bank conflicts).

#define K_DIM 1024
#define N_DIM 4096
#define B_DIM 4096
#define NQ 12

typedef __attribute__((ext_vector_type(8))) _Float16 f16x8;
typedef __attribute__((ext_vector_type(4))) float f32x4;

// Tile layout (A and B^T): tile = 128 rows x 64 k of f16 = 16384 bytes.
// tile(tr, kt) at ((tr*16)+kt)*16384. Element (r, kk) at byte
//   ((r<<7) + (kk<<1)) ^ ((r&7)<<4)          (bijective XOR, 16B-granular)

// ---------------- phase mean ----------------
__global__ void pm_kernel(const float* __restrict__ phases, float* __restrict__ pm) {
    int j = blockIdx.x * 256 + threadIdx.x;
    if (j < K_DIM) {
        float s = 0.f;
#pragma unroll
        for (int q = 0; q < NQ; ++q) s += phases[j * NQ + q];
        pm[j] = s * (1.0f / NQ);
    }
}

// ---------------- A producer: coef = cos(x*pm) -> f16, tiled+swizzled ----------------
__global__ void asplit_kernel(const float* __restrict__ x, const float* __restrict__ pm,
                              char* __restrict__ Ah) {
    int i = blockIdx.x * 256 + threadIdx.x;    // one thread per 8 consecutive k
    int row = i >> 7;                          // 0..4095  (128 threads per row)
    int k0  = (i & 127) << 3;                  // 0..1016
    const float* xp = x + ((size_t)row << 10) + k0;
    float4 xa = *(const float4*)xp;
    float4 xb = *(const float4*)(xp + 4);
    float4 pa = *(const float4*)(pm + k0);
    float4 pb = *(const float4*)(pm + k0 + 4);
    f16x8 hv;
    hv[0] = (_Float16)__cosf(xa.x * pa.x); hv[1] = (_Float16)__cosf(xa.y * pa.y);
    hv[2] = (_Float16)__cosf(xa.z * pa.z); hv[3] = (_Float16)__cosf(xa.w * pa.w);
    hv[4] = (_Float16)__cosf(xb.x * pb.x); hv[5] = (_Float16)__cosf(xb.y * pb.y);
    hv[6] = (_Float16)__cosf(xb.z * pb.z); hv[7] = (_Float16)__cosf(xb.w * pb.w);
    int tm = row >> 7, kt = k0 >> 6;
    int r = row & 127, kk = k0 & 63;
    size_t base = ((size_t)tm * 16 + (size_t)kt) * 16384;
    int addr = ((r << 7) + (kk << 1)) ^ ((r & 7) << 4);   // 16B aligned
    *(f16x8*)(Ah + base + addr) = hv;
}

// ---------------- W producer: transpose [K][N] -> [N][K] f16, tiled+swizzled ----------------
__global__ void wsplit_kernel(const float* __restrict__ W, char* __restrict__ Bf) {
    __shared__ float t[64][65];
    int n0 = blockIdx.x * 64, k0 = blockIdx.y * 64;
    int tid = threadIdx.x;
#pragma unroll
    for (int p = 0; p < 16; ++p) {
        int lin = p * 256 + tid;
        int kk = lin >> 6, nn = lin & 63;
        t[kk][nn] = W[(size_t)(k0 + kk) * N_DIM + n0 + nn];   // coalesced in n
    }
    __syncthreads();
    size_t base = ((size_t)(n0 >> 7) * 16 + (size_t)blockIdx.y) * 16384;
#pragma unroll
    for (int p2 = 0; p2 < 2; ++p2) {
        int w = p2 * 256 + tid;
        int nn = w >> 3, oct = w & 7;       // 64 n-rows x 8 k-octets
        int r = (n0 & 127) + nn;            // row within 128-row tile
        f16x8 hv;
#pragma unroll
        for (int j = 0; j < 8; ++j) hv[j] = (_Float16)t[oct * 8 + j][nn];
        int addr = ((r << 7) + (oct << 4)) ^ ((r & 7) << 4);
        *(f16x8*)(Bf + base + addr) = hv;   // 16B store
    }
}

// ---------------- GEMM: 128x128 tile, BK=64, 4 waves, single-term f16 ----------------
#define GLL16(g, l)                                                           \
    __builtin_amdgcn_global_load_lds(                                         \
        (const __attribute__((address_space(1))) void*)(g),                   \
        (__attribute__((address_space(3))) void*)(l), 16, 0, 0)

__global__ __launch_bounds__(256, 2) void gemm_kernel(
        const char* __restrict__ Ah, const char* __restrict__ Bf,
        float* __restrict__ C) {
    __shared__ char lds[32768];   // A @0, B @16384 (swizzled tile images)
    const int tid  = threadIdx.x;
    const int lane = tid & 63;
    const int wid  = tid >> 6;
    const int wr = wid >> 1, wc = wid & 1;       // 2x2 waves -> 64x64 out each
    const int fr   = lane & 15;
    const int colb = (lane >> 4) << 4;           // byte offset of lane's 8-f16 k-group

    // XCD chunk swizzle: 1024 wgs, 8 XCDs, 128/XCD (bijective). Consecutive-
    // on-XCD blocks share the A row-panel (same by) -> per-XCD L2 locality.
    int wg  = blockIdx.x;
    int swz = (wg & 7) * 128 + (wg >> 3);
    const int by = swz >> 5;        // 0..31 (M tiles of 128)
    const int bx = swz & 31;        // 0..31 (N tiles of 128)

    const char* pA = Ah + (size_t)by * 16 * 16384;
    const char* pB = Bf + (size_t)bx * 16 * 16384;

    int aAddr[4][2], bAddr[4][2];
#pragma unroll
    for (int m = 0; m < 4; ++m) {
        int r = wr * 64 + m * 16 + fr;
#pragma unroll
        for (int kh = 0; kh < 2; ++kh)
            aAddr[m][kh] = ((r << 7) + kh * 64 + colb) ^ ((r & 7) << 4);
    }
#pragma unroll
    for (int n = 0; n < 4; ++n) {
        int r = wc * 64 + n * 16 + fr;
#pragma unroll
        for (int kh = 0; kh < 2; ++kh)
            bAddr[n][kh] = ((r << 7) + kh * 64 + colb) ^ ((r & 7) << 4);
    }

    f32x4 acc[4][4];
#pragma unroll
    for (int m = 0; m < 4; ++m)
#pragma unroll
        for (int n = 0; n < 4; ++n)
            acc[m][n] = (f32x4){0.f, 0.f, 0.f, 0.f};

    for (int kt = 0; kt < K_DIM / 64; ++kt) {
        // stage 2 x 16KB swizzled tile images, linear copies
#pragma unroll
        for (int p = 0; p < 4; ++p) {
            int off = p * 4096 + (tid << 4);
            GLL16(pA + off, lds + off);
            GLL16(pB + off, lds + 16384 + off);
        }
        pA += 16384; pB += 16384;
        __syncthreads();   // drains vmcnt -> tiles resident

#pragma unroll
        for (int kh = 0; kh < 2; ++kh) {
            f16x8 aH[4], bF[4];
#pragma unroll
            for (int m = 0; m < 4; ++m)
                aH[m] = *(const f16x8*)(lds + aAddr[m][kh]);
#pragma unroll
            for (int n = 0; n < 4; ++n)
                bF[n] = *(const f16x8*)(lds + 16384 + bAddr[n][kh]);
#pragma unroll
            for (int m = 0; m < 4; ++m)
#pragma unroll
                for (int n = 0; n < 4; ++n)
                    acc[m][n] = __builtin_amdgcn_mfma_f32_16x16x32_f16(
                        aH[m], bF[n], acc[m][n], 0, 0, 0);
        }
        __syncthreads();   // compute done before next stage overwrites
    }

    // epilogue: C/D layout col = lane&15, row = (lane>>4)*4 + j  (m91-verified)
    const int crow0 = by * 128 + wr * 64 + ((lane >> 4) << 2);
    const int ccol0 = bx * 128 + wc * 64 + fr;
#pragma unroll
    for (int m = 0; m < 4; ++m)
#pragma unroll
        for (int n = 0; n < 4; ++n) {
            size_t base = (size_t)(crow0 + m * 16) * N_DIM + (size_t)(ccol0 + n * 16);
#pragma unroll
            for (int j = 0; j < 4; ++j)
                C[base + (size_t)j * N_DIM] = acc[m][n][j];
        }
}

extern "C" void kernel_launch(void* const* d_in, const int* in_sizes, int n_in,
                              void* d_out, int out_size, void* d_ws, size_t ws_size,
                              hipStream_t stream) {
    const float* x      = (const float*)d_in[0];   // [4096,1024]
    const float* W      = (const float*)d_in[1];   // [1024,4096]
    const float* phases = (const float*)d_in[2];   // [1024,12]
    float* out = (float*)d_out;                    // [4096,4096] f32

    char* ws = (char*)d_ws;
    float* pm = (float*)ws;                               // 4 KB
    char* Ah = ws + 65536;                                // 8 MB
    char* Bf = Ah + (size_t)8 * 1024 * 1024;              // 8 MB
    // total ws use: 64 KB + 16 MB

    pm_kernel<<<4, 256, 0, stream>>>(phases, pm);
    asplit_kernel<<<(B_DIM * (K_DIM / 8)) / 256, 256, 0, stream>>>(x, pm, Ah);
    wsplit_kernel<<<dim3(N_DIM / 64, K_DIM / 64), 256, 0, stream>>>(W, Bf);
    gemm_kernel<<<1024, 256, 0, stream>>>(Ah, Bf, out);
}

// Round 8
// 127.534 us; speedup vs baseline: 1.0853x; 1.0853x over previous
//
#include <hip/hip_runtime.h>
#include <hip/hip_bf16.h>

// out[b,n] = sum_k cos(x[b,k] * mean(phases[k,:])) * W[k,n]
// B = 4096, K = 1024, N = 4096, NQ = 12. All fp32 in/out.
//
// Round 8: single-term f16. Evidence (r3 vs r7): wall = Nkt x (fixed-stage-cost
// + MFMA); only r3's 64-MFMA-per-wave-per-K-tile ratio exceeded 1 PF effective.
// Restore that ratio at single-term cost: block 256(M)x128(N), BK=64, stage
// A0+A1+B (48 KB, 3 blocks/CU), 4 waves each 128x64 out = 64 MFMA/wave/K-tile.
// Same staged bytes and MFMA-per-barrier as r3, double the output per block.
// Proven 2-barrier schedule; producers byte-identical to r7 (zero conflicts).

#define K_DIM 1024
#define N_DIM 4096
#define B_DIM 4096
#define NQ 12

typedef __attribute__((ext_vector_type(8))) _Float16 f16x8;
typedef __attribute__((ext_vector_type(4))) float f32x4;

// Tile layout (A and B^T): tile = 128 rows x 64 k of f16 = 16384 bytes.
// tile(tr, kt) at ((tr*16)+kt)*16384. Element (r, kk) at byte
//   ((r<<7) + (kk<<1)) ^ ((r&7)<<4)          (bijective XOR, 16B-granular)

// ---------------- phase mean ----------------
__global__ void pm_kernel(const float* __restrict__ phases, float* __restrict__ pm) {
    int j = blockIdx.x * 256 + threadIdx.x;
    if (j < K_DIM) {
        float s = 0.f;
#pragma unroll
        for (int q = 0; q < NQ; ++q) s += phases[j * NQ + q];
        pm[j] = s * (1.0f / NQ);
    }
}

// ---------------- A producer: coef = cos(x*pm) -> f16, tiled+swizzled ----------------
__global__ void asplit_kernel(const float* __restrict__ x, const float* __restrict__ pm,
                              char* __restrict__ Ah) {
    int i = blockIdx.x * 256 + threadIdx.x;    // one thread per 8 consecutive k
    int row = i >> 7;                          // 0..4095  (128 threads per row)
    int k0  = (i & 127) << 3;                  // 0..1016
    const float* xp = x + ((size_t)row << 10) + k0;
    float4 xa = *(const float4*)xp;
    float4 xb = *(const float4*)(xp + 4);
    float4 pa = *(const float4*)(pm + k0);
    float4 pb = *(const float4*)(pm + k0 + 4);
    f16x8 hv;
    hv[0] = (_Float16)__cosf(xa.x * pa.x); hv[1] = (_Float16)__cosf(xa.y * pa.y);
    hv[2] = (_Float16)__cosf(xa.z * pa.z); hv[3] = (_Float16)__cosf(xa.w * pa.w);
    hv[4] = (_Float16)__cosf(xb.x * pb.x); hv[5] = (_Float16)__cosf(xb.y * pb.y);
    hv[6] = (_Float16)__cosf(xb.z * pb.z); hv[7] = (_Float16)__cosf(xb.w * pb.w);
    int tm = row >> 7, kt = k0 >> 6;
    int r = row & 127, kk = k0 & 63;
    size_t base = ((size_t)tm * 16 + (size_t)kt) * 16384;
    int addr = ((r << 7) + (kk << 1)) ^ ((r & 7) << 4);   // 16B aligned
    *(f16x8*)(Ah + base + addr) = hv;
}

// ---------------- W producer: transpose [K][N] -> [N][K] f16, tiled+swizzled ----------------
__global__ void wsplit_kernel(const float* __restrict__ W, char* __restrict__ Bf) {
    __shared__ float t[64][65];
    int n0 = blockIdx.x * 64, k0 = blockIdx.y * 64;
    int tid = threadIdx.x;
#pragma unroll
    for (int p = 0; p < 16; ++p) {
        int lin = p * 256 + tid;
        int kk = lin >> 6, nn = lin & 63;
        t[kk][nn] = W[(size_t)(k0 + kk) * N_DIM + n0 + nn];   // coalesced in n
    }
    __syncthreads();
    size_t base = ((size_t)(n0 >> 7) * 16 + (size_t)blockIdx.y) * 16384;
#pragma unroll
    for (int p2 = 0; p2 < 2; ++p2) {
        int w = p2 * 256 + tid;
        int nn = w >> 3, oct = w & 7;       // 64 n-rows x 8 k-octets
        int r = (n0 & 127) + nn;            // row within 128-row tile
        f16x8 hv;
#pragma unroll
        for (int j = 0; j < 8; ++j) hv[j] = (_Float16)t[oct * 8 + j][nn];
        int addr = ((r << 7) + (oct << 4)) ^ ((r & 7) << 4);
        *(f16x8*)(Bf + base + addr) = hv;   // 16B store
    }
}

// ---------------- GEMM: 256x128 block, BK=64, 4 waves (wave = 128x64 out) ----------------
#define GLL16(g, l)                                                           \
    __builtin_amdgcn_global_load_lds(                                         \
        (const __attribute__((address_space(1))) void*)(g),                   \
        (__attribute__((address_space(3))) void*)(l), 16, 0, 0)

__global__ __launch_bounds__(256, 2) void gemm_kernel(
        const char* __restrict__ Ah, const char* __restrict__ Bf,
        float* __restrict__ C) {
    __shared__ char lds[49152];   // A-rows0-127 @0, A-rows128-255 @16384, B @32768
    const int tid  = threadIdx.x;
    const int lane = tid & 63;
    const int wid  = tid >> 6;
    const int wr = wid >> 1, wc = wid & 1;     // 2x2 waves; wave = 128(M)x64(N) out
    const int fr   = lane & 15;
    const int colb = (lane >> 4) << 4;         // byte offset of lane's 8-f16 k-group

    // XCD chunk swizzle: 512 wgs, 8 XCDs, 64/XCD (bijective). Consecutive-
    // on-XCD blocks share the A row-panel (same by) -> per-XCD L2 locality.
    int wg  = blockIdx.x;
    int swz = (wg & 7) * 64 + (wg >> 3);
    const int by = swz >> 5;        // 0..15 (M tiles of 256)
    const int bx = swz & 31;        // 0..31 (N tiles of 128)

    const char* pA0 = Ah + (size_t)(by * 2)     * 16 * 16384;
    const char* pA1 = Ah + (size_t)(by * 2 + 1) * 16 * 16384;
    const char* pB  = Bf + (size_t)bx * 16 * 16384;

    // A fragment addrs: wave rows wr*128 + m*16 + fr, m=0..7 (spans both A tiles)
    int aAddr[8][2], bAddr[4][2];
#pragma unroll
    for (int m = 0; m < 8; ++m) {
        int r  = wr * 128 + m * 16 + fr;
        int ts = r >> 7, rr = r & 127;
#pragma unroll
        for (int kh = 0; kh < 2; ++kh)
            aAddr[m][kh] = ts * 16384 + (((rr << 7) + kh * 64 + colb) ^ ((rr & 7) << 4));
    }
#pragma unroll
    for (int n = 0; n < 4; ++n) {
        int r = wc * 64 + n * 16 + fr;
#pragma unroll
        for (int kh = 0; kh < 2; ++kh)
            bAddr[n][kh] = 32768 + (((r << 7) + kh * 64 + colb) ^ ((r & 7) << 4));
    }

    f32x4 acc[8][4];
#pragma unroll
    for (int m = 0; m < 8; ++m)
#pragma unroll
        for (int n = 0; n < 4; ++n)
            acc[m][n] = (f32x4){0.f, 0.f, 0.f, 0.f};

    for (int kt = 0; kt < K_DIM / 64; ++kt) {
        // stage 3 x 16KB swizzled tile images, linear copies
#pragma unroll
        for (int p = 0; p < 4; ++p) {
            int off = p * 4096 + (tid << 4);
            GLL16(pA0 + off, lds + off);
            GLL16(pA1 + off, lds + 16384 + off);
            GLL16(pB  + off, lds + 32768 + off);
        }
        pA0 += 16384; pA1 += 16384; pB += 16384;
        __syncthreads();   // drains vmcnt -> tiles resident

#pragma unroll
        for (int kh = 0; kh < 2; ++kh) {
            f16x8 aH[8], bF[4];
#pragma unroll
            for (int n = 0; n < 4; ++n)
                bF[n] = *(const f16x8*)(lds + bAddr[n][kh]);
#pragma unroll
            for (int m = 0; m < 8; ++m)
                aH[m] = *(const f16x8*)(lds + aAddr[m][kh]);
#pragma unroll
            for (int m = 0; m < 8; ++m)
#pragma unroll
                for (int n = 0; n < 4; ++n)
                    acc[m][n] = __builtin_amdgcn_mfma_f32_16x16x32_f16(
                        aH[m], bF[n], acc[m][n], 0, 0, 0);
        }
        __syncthreads();   // compute done before next stage overwrites
    }

    // epilogue: C/D layout col = lane&15, row = (lane>>4)*4 + j  (m91-verified)
    const int crow0 = by * 256 + wr * 128 + ((lane >> 4) << 2);
    const int ccol0 = bx * 128 + wc * 64 + fr;
#pragma unroll
    for (int m = 0; m < 8; ++m)
#pragma unroll
        for (int n = 0; n < 4; ++n) {
            size_t base = (size_t)(crow0 + m * 16) * N_DIM + (size_t)(ccol0 + n * 16);
#pragma unroll
            for (int j = 0; j < 4; ++j)
                C[base + (size_t)j * N_DIM] = acc[m][n][j];
        }
}

extern "C" void kernel_launch(void* const* d_in, const int* in_sizes, int n_in,
                              void* d_out, int out_size, void* d_ws, size_t ws_size,
                              hipStream_t stream) {
    const float* x      = (const float*)d_in[0];   // [4096,1024]
    const float* W      = (const float*)d_in[1];   // [1024,4096]
    const float* phases = (const float*)d_in[2];   // [1024,12]
    float* out = (float*)d_out;                    // [4096,4096] f32

    char* ws = (char*)d_ws;
    float* pm = (float*)ws;                               // 4 KB
    char* Ah = ws + 65536;                                // 8 MB
    char* Bf = Ah + (size_t)8 * 1024 * 1024;              // 8 MB
    // total ws use: 64 KB + 16 MB

    pm_kernel<<<4, 256, 0, stream>>>(phases, pm);
    asplit_kernel<<<(B_DIM * (K_DIM / 8)) / 256, 256, 0, stream>>>(x, pm, Ah);
    wsplit_kernel<<<dim3(N_DIM / 64, K_DIM / 64), 256, 0, stream>>>(W, Bf);
    gemm_kernel<<<512, 256, 0, stream>>>(Ah, Bf, out);
}